// Round 2
// baseline (122.454 us; speedup 1.0000x reference)
//
#include <hip/hip_runtime.h>
#include <math.h>

#define HH 512
#define WW 512
#define NA 180
#define ND 729
#define NB 2

// ws layout (float units):
//   [0, 729)                 g (spatial filter kernel)
//   [1024, 1024+180)         cos table
//   [1280, 1280+180)         sin table
//   [2048, 2048 + NB*NA*ND)  filtered sinograms
#define WS_COS 1024
#define WS_SIN 1280
#define WS_FILT 2048

// g[n] = (1/D) * [0.25 - sum_{odd k} cos(2*pi*k*n/D)/(pi^2 k^2)]
// exact phase reduction via (k*n) mod D, double-precision cos.
// Block ND computes the angle tables instead (merged launch).
__global__ __launch_bounds__(64) void k_tables(float* __restrict__ ws) {
    int n = blockIdx.x;          // 0..729
    int lane = threadIdx.x;      // 0..63
    if (n == ND) {               // angle-table block
        for (int t = lane; t < NA; t += 64) {
            double ang = M_PI * (double)t / (double)(NA - 1);  // linspace(0, pi, 180)
            ws[WS_COS + t] = (float)cos(ang);
            ws[WS_SIN + t] = (float)sin(ang);
        }
        return;
    }
    double acc = 0.0;
    for (int j = lane; j < 364; j += 64) {
        int k = 2 * j + 1;
        int t = (k * n) % ND;
        double ang = (2.0 * M_PI) * (double)t / (double)ND;
        acc -= cos(ang) / (M_PI * M_PI * (double)k * (double)k);
    }
    for (int off = 32; off > 0; off >>= 1)
        acc += __shfl_down(acc, off, 64);
    if (lane == 0) {
        acc += 0.25;
        ws[n] = (float)(acc / (double)ND);
    }
}

// Circular convolution: filtered[row][n] = sum_m x[row][m] * g[(n-m) mod D].
// Register-blocked 4 outputs x 4 m's per iteration:
//   needed g values form the 7-wide window g[(n-m-3 .. n-m+3) mod D]
//   = ga[B .. B+6] with ga[i] = g[(i+727) mod D], B = n-m+728 (B = 0 mod 4).
//   Two aligned b128 reads cover the window; x[m..m+3] is one broadcast b128.
__global__ __launch_bounds__(192) void k_filter(const float* __restrict__ sino,
                                                float* __restrict__ ws) {
    __shared__ float xs[736];    // x zero-padded to 736
    __shared__ float ga[1464];   // shifted wrapped copy of g
    int row = blockIdx.x;        // b*NA + a
    int tid = threadIdx.x;
    const float* x = sino + row * ND;
    for (int i = tid; i < 736; i += 192) xs[i] = (i < ND) ? x[i] : 0.0f;
    for (int i = tid; i < 1464; i += 192) ga[i] = ws[(i + 727) % ND];
    __syncthreads();
    int t = (tid < 183) ? tid : 0;   // threads >=183 compute row-0 slice redundantly, no store
    int n = 4 * t;
    float a0 = 0.f, a1 = 0.f, a2 = 0.f, a3 = 0.f;
    for (int m = 0; m < ND; m += 4) {
        float4 xv = *(const float4*)&xs[m];       // broadcast
        int B = n - m + 728;                      // 0-aligned, in [0,1456]
        float4 gA = *(const float4*)&ga[B];       // w[0..3]
        float4 gB = *(const float4*)&ga[B + 4];   // w[4..7]
        // acc[dn] += sum_dm xv[dm] * w[3+dn-dm]
        a0 += xv.x * gA.w + xv.y * gA.z + xv.z * gA.y + xv.w * gA.x;
        a1 += xv.x * gB.x + xv.y * gA.w + xv.z * gA.z + xv.w * gA.y;
        a2 += xv.x * gB.y + xv.y * gB.x + xv.z * gA.w + xv.w * gA.z;
        a3 += xv.x * gB.z + xv.y * gB.y + xv.z * gB.x + xv.w * gA.w;
    }
    if (tid < 183) {
        float* f = ws + WS_FILT + row * ND;
        f[n] = a0;
        if (n + 1 < ND) f[n + 1] = a1;
        if (n + 2 < ND) f[n + 2] = a2;
        if (n + 3 < ND) f[n + 3] = a3;
    }
}

__global__ __launch_bounds__(256) void k_bp(const float* __restrict__ ws,
                                            float* __restrict__ out) {
    __shared__ float cs[NA], sn[NA];
    int tid = threadIdx.x;
    if (tid < NA) { cs[tid] = ws[WS_COS + tid]; sn[tid] = ws[WS_SIN + tid]; }
    __syncthreads();
    int p = blockIdx.x * 256 + tid;       // < NB*HH*WW
    int b = p / (HH * WW);
    int rem = p - b * (HH * WW);
    int y = rem / WW;
    int x = rem - y * WW;
    float xc = (float)x - (WW * 0.5f);
    float yc = (float)y - (HH * 0.5f);
    const float* f = ws + WS_FILT + b * (NA * ND);
    float acc = 0.f;
    #pragma unroll 4
    for (int a = 0; a < NA; ++a) {
        float rot = xc * cs[a] + yc * sn[a];
        float t = (rot * 0.15915494309189535f) * 729.0f;  // rot/(2pi)*D
        int i = (int)t;                                   // trunc toward zero, matches astype(int32)
        i = i < 0 ? 0 : (i > (ND - 1) ? (ND - 1) : i);
        acc += f[a * ND + i];
    }
    out[p] = fmaxf(acc * (float)(M_PI / NA), 0.0f);       // clip(·, 0, max) == relu (max >= 0)
}

extern "C" void kernel_launch(void* const* d_in, const int* in_sizes, int n_in,
                              void* d_out, int out_size, void* d_ws, size_t ws_size,
                              hipStream_t stream) {
    const float* sino = (const float*)d_in[0];
    float* out = (float*)d_out;
    float* ws = (float*)d_ws;

    hipLaunchKernelGGL(k_tables, dim3(ND + 1), dim3(64), 0, stream, ws);
    hipLaunchKernelGGL(k_filter, dim3(NB * NA), dim3(192), 0, stream, sino, ws);
    hipLaunchKernelGGL(k_bp, dim3((NB * HH * WW) / 256), dim3(256), 0, stream, ws, out);
}

// Round 3
// 113.850 us; speedup vs baseline: 1.0756x; 1.0756x over previous
//
#include <hip/hip_runtime.h>
#include <math.h>

#define HH 512
#define WW 512
#define NA 180
#define ND 729
#define NB 2

// ws layout (float units):
//   [1024, 1024+360)         interleaved {cos,sin} per angle
//   [2048, 2048 + NB*NA*ND)  filtered sinograms
#define WS_CS 1024
#define WS_FILT 2048

// Filter kernel (exact closed form):
//   g[n] = (1/D) * [0.25 - (1/pi^2) * sum_{odd k} cos(2 pi k n / D)/k^2]
//   sum_{k odd} cos(k t)/k^2 = pi^2/8 - pi*t/4  on t in [0,pi]  (infinite sum;
//   truncation tail of the finite k<=727 sum is <= 7e-8 per tap -> negligible)
//   => g[n] = (0.125 + min(n, D-n)/1458) / 729
__device__ __forceinline__ float g_of(int n) {   // n in [0, ND)
    int m = n < (ND - n) ? n : (ND - n);
    return (float)((0.125 + (double)m * (1.0 / 1458.0)) * (1.0 / 729.0));
}

// Circular convolution: filtered[row][n] = sum_m x[row][m] * g[(n-m) mod D].
// Register-blocked 4 outputs x 4 m's per iteration; ga is the shifted wrapped
// copy of g so both b128 reads are 16B-aligned (n-m == 0 mod 4 always).
// Block NB*NA computes the angle tables instead (merged launch).
__global__ __launch_bounds__(192) void k_filter(const float* __restrict__ sino,
                                                float* __restrict__ ws) {
    int row = blockIdx.x;        // b*NA + a, or NB*NA for the angle block
    int tid = threadIdx.x;
    if (row == NB * NA) {
        for (int t = tid; t < NA; t += 192) {
            double ang = M_PI * (double)t / (double)(NA - 1);  // linspace(0, pi, 180)
            ws[WS_CS + 2 * t] = (float)cos(ang);
            ws[WS_CS + 2 * t + 1] = (float)sin(ang);
        }
        return;
    }
    __shared__ float xs[736];    // x zero-padded to 736
    __shared__ float ga[1464];   // ga[i] = g[(i+727) mod D]
    const float* x = sino + row * ND;
    for (int i = tid; i < 736; i += 192) xs[i] = (i < ND) ? x[i] : 0.0f;
    for (int i = tid; i < 1464; i += 192) ga[i] = g_of((i + 727) % ND);
    __syncthreads();
    int t = (tid < 183) ? tid : 0;   // threads >=183 compute row-slice-0 redundantly, no store
    int n = 4 * t;
    float a0 = 0.f, a1 = 0.f, a2 = 0.f, a3 = 0.f;
    #pragma unroll 4
    for (int m = 0; m < ND; m += 4) {
        float4 xv = *(const float4*)&xs[m];       // broadcast
        int B = n - m + 728;                      // 4-aligned, in [0,1456]
        float4 gA = *(const float4*)&ga[B];       // w[0..3]
        float4 gB = *(const float4*)&ga[B + 4];   // w[4..7]
        // acc[dn] += sum_dm xv[dm] * w[3+dn-dm]
        a0 += xv.x * gA.w + xv.y * gA.z + xv.z * gA.y + xv.w * gA.x;
        a1 += xv.x * gB.x + xv.y * gA.w + xv.z * gA.z + xv.w * gA.y;
        a2 += xv.x * gB.y + xv.y * gB.x + xv.z * gA.w + xv.w * gA.z;
        a3 += xv.x * gB.z + xv.y * gB.y + xv.z * gB.x + xv.w * gA.w;
    }
    if (tid < 183) {
        float* f = ws + WS_FILT + row * ND;
        f[n] = a0;
        if (n + 1 < ND) f[n + 1] = a1;
        if (n + 2 < ND) f[n + 2] = a2;
        if (n + 3 < ND) f[n + 3] = a3;
    }
}

__global__ __launch_bounds__(256) void k_bp(const float* __restrict__ ws,
                                            float* __restrict__ out) {
    const float* __restrict__ tab = ws + WS_CS;   // wave-uniform reads -> s_load
    int tid = threadIdx.x;
    int p = blockIdx.x * 256 + tid;       // < NB*HH*WW
    int b = p / (HH * WW);
    int rem = p - b * (HH * WW);
    int y = rem / WW;
    int x = rem - y * WW;
    float xc = (float)x - (WW * 0.5f);
    float yc = (float)y - (HH * 0.5f);
    const float* f = ws + WS_FILT + b * (NA * ND);
    float acc = 0.f;
    #pragma unroll 4
    for (int a = 0; a < NA; ++a) {
        float c = tab[2 * a];
        float s = tab[2 * a + 1];
        float rot = xc * c + yc * s;
        float t = (rot * 0.15915494309189535f) * 729.0f;  // rot/(2pi)*D
        int i = (int)t;                                   // trunc toward zero, matches astype(int32)
        i = i < 0 ? 0 : (i > (ND - 1) ? (ND - 1) : i);
        acc += f[a * ND + i];
    }
    out[p] = fmaxf(acc * (float)(M_PI / NA), 0.0f);       // clip(·, 0, max) == relu (max >= 0)
}

extern "C" void kernel_launch(void* const* d_in, const int* in_sizes, int n_in,
                              void* d_out, int out_size, void* d_ws, size_t ws_size,
                              hipStream_t stream) {
    const float* sino = (const float*)d_in[0];
    float* out = (float*)d_out;
    float* ws = (float*)d_ws;

    hipLaunchKernelGGL(k_filter, dim3(NB * NA + 1), dim3(192), 0, stream, sino, ws);
    hipLaunchKernelGGL(k_bp, dim3((NB * HH * WW) / 256), dim3(256), 0, stream, ws, out);
}

// Round 4
// 111.170 us; speedup vs baseline: 1.1015x; 1.0241x over previous
//
#include <hip/hip_runtime.h>
#include <math.h>

#define HH 512
#define WW 512
#define NA 180
#define ND 729
#define NB 2

// ws layout (float units):
//   [1024, 1024+360)   interleaved {cos,sin} per angle
//   [2048 + b*192)     P0[b][0..180]   (exclusive prefix of f[b][a][0])
//   [2560 + b*192)     P728[b][0..180] (exclusive prefix of f[b][a][728])
//   [4096, ...)        filtered sinograms
#define WS_CS 1024
#define WS_P0 2048
#define WS_P728 2560
#define WS_FILT 4096

// Filter kernel (closed form):
//   g[n] = (0.125 + min(n, D-n)/1458) / 729   (tail of truncated odd-k sum < 7e-8/tap)
__device__ __forceinline__ float g_of(int n) {
    int m = n < (ND - n) ? n : (ND - n);
    return (float)((0.125 + (double)m * (1.0 / 1458.0)) * (1.0 / 729.0));
}

// Circular convolution, register-blocked 4x4. Block NB*NA does angle tables.
__global__ __launch_bounds__(192) void k_filter(const float* __restrict__ sino,
                                                float* __restrict__ ws) {
    int row = blockIdx.x;
    int tid = threadIdx.x;
    if (row == NB * NA) {
        for (int t = tid; t < NA; t += 192) {
            double ang = M_PI * (double)t / (double)(NA - 1);
            ws[WS_CS + 2 * t] = (float)cos(ang);
            ws[WS_CS + 2 * t + 1] = (float)sin(ang);
        }
        return;
    }
    __shared__ float xs[736];
    __shared__ float ga[1464];   // ga[i] = g[(i+727) mod D]
    const float* x = sino + row * ND;
    for (int i = tid; i < 736; i += 192) xs[i] = (i < ND) ? x[i] : 0.0f;
    for (int i = tid; i < 1464; i += 192) ga[i] = g_of((i + 727) % ND);
    __syncthreads();
    int t = (tid < 183) ? tid : 0;
    int n = 4 * t;
    float a0 = 0.f, a1 = 0.f, a2 = 0.f, a3 = 0.f;
    #pragma unroll 4
    for (int m = 0; m < ND; m += 4) {
        float4 xv = *(const float4*)&xs[m];
        int B = n - m + 728;
        float4 gA = *(const float4*)&ga[B];
        float4 gB = *(const float4*)&ga[B + 4];
        a0 += xv.x * gA.w + xv.y * gA.z + xv.z * gA.y + xv.w * gA.x;
        a1 += xv.x * gB.x + xv.y * gA.w + xv.z * gA.z + xv.w * gA.y;
        a2 += xv.x * gB.y + xv.y * gB.x + xv.z * gA.w + xv.w * gA.z;
        a3 += xv.x * gB.z + xv.y * gB.y + xv.z * gB.x + xv.w * gA.w;
    }
    if (tid < 183) {
        float* f = ws + WS_FILT + row * ND;
        f[n] = a0;
        if (n + 1 < ND) f[n + 1] = a1;
        if (n + 2 < ND) f[n + 2] = a2;
        if (n + 3 < ND) f[n + 3] = a3;
    }
}

// Exclusive prefix sums of f[b][a][0] and f[b][a][728] over a. One block.
__global__ __launch_bounds__(256) void k_prefix(float* __restrict__ ws) {
    __shared__ float buf[256];
    int tid = threadIdx.x;
    for (int q = 0; q < 4; ++q) {
        int b = q >> 1;
        int col = (q & 1) ? (ND - 1) : 0;
        float v = 0.f;
        if (tid < NA) v = ws[WS_FILT + (b * NA + tid) * ND + col];
        buf[tid] = v;
        __syncthreads();
        for (int off = 1; off < 256; off <<= 1) {
            float add = (tid >= off) ? buf[tid - off] : 0.f;
            __syncthreads();
            buf[tid] += add;
            __syncthreads();
        }
        int base = ((q & 1) ? WS_P728 : WS_P0) + b * 192;
        if (tid == 0) ws[base] = 0.f;
        if (tid < NA) ws[base + tid + 1] = buf[tid];
        __syncthreads();
    }
}

// Backprojection. idx(a) = clip(trunc((rot*c1)*729), 0, 728), rot = xc*cos+yc*sin.
// For r>=16 the angle axis splits into [low | band | high | band | low] intervals:
//   high (idx=728): rot >= 6.27457  <=>  |a-phi| <= theta, theta = acos(6.27457/r)
//   low  (idx=0):   rot <  0.008619 <=>  |a-phi| >  ~pi/2
// Interval edges predicted via atan2f/acosf (error ~1e-3 index units), guarded by
// +-1 index; guarded band evaluated with the exact original arithmetic; clamped
// cores use prefix sums (per-index rot step >= r*h*sin(theta) >= 0.25 >> any
// float error, so the +-1 guard is sound).
__global__ __launch_bounds__(256) void k_bp(const float* __restrict__ ws,
                                            float* __restrict__ out) {
    const float* __restrict__ tab = ws + WS_CS;
    int tid = threadIdx.x;
    int p = blockIdx.x * 256 + tid;
    int b = p / (HH * WW);
    int rem = p - b * (HH * WW);
    int y = rem / WW;
    int x = rem - y * WW;
    float xc = (float)x - (WW * 0.5f);
    float yc = (float)y - (HH * 0.5f);
    const float* f = ws + WS_FILT + b * (NA * ND);
    float acc = 0.f;
    float r2 = xc * xc + yc * yc;
    if (r2 < 256.0f) {
        // exact fallback (r < 16): ~800 central pixels
        for (int a = 0; a < NA; ++a) {
            float c = tab[2 * a], s = tab[2 * a + 1];
            float rot = xc * c + yc * s;
            float t = (rot * 0.15915494309189535f) * 729.0f;
            int i = (int)t;
            i = i < 0 ? 0 : (i > (ND - 1) ? (ND - 1) : i);
            acc += f[a * ND + i];
        }
    } else {
        float r = sqrtf(r2);
        float phi = atan2f(yc, xc);
        float cen = (phi < -1.5707964f) ? phi + 6.2831855f : phi;  // unique arc center
        float theta = acosf(6.27457f / r);                          // <= 1.168 (r>=16)
        float tc = cen * 56.971835f;                                // *(179/pi)
        float w = theta * 56.971835f;
        int hs = (int)ceilf(tc - w) + 1;        // guaranteed-high core [hs, he]
        int he = (int)floorf(tc + w) - 1;
        int le = (int)floorf(tc - 89.5f) - 1;   // guaranteed-low [0, le]
        int rs = (int)ceilf(tc + 89.5f) + 1;    // guaranteed-low [rs, 179]
        hs = hs < 0 ? 0 : hs;
        he = he > (NA - 1) ? (NA - 1) : he;
        const float* P0 = ws + WS_P0 + b * 192;
        const float* P728 = ws + WS_P728 + b * 192;
        if (le >= 0) acc += P0[le + 1];
        if (rs <= NA - 1) acc += P0[NA] - P0[rs];
        if (he >= hs) acc += P728[he + 1] - P728[hs];
        int b1s = le + 1 < 0 ? 0 : le + 1;
        int b1e = hs - 1 > (NA - 1) ? (NA - 1) : hs - 1;
        int b2s = he + 1 < 0 ? 0 : he + 1;
        int b2e = rs - 1 > (NA - 1) ? (NA - 1) : rs - 1;
        for (int a = b1s; a <= b1e; ++a) {
            float c = tab[2 * a], s = tab[2 * a + 1];
            float rot = xc * c + yc * s;
            float t = (rot * 0.15915494309189535f) * 729.0f;
            int i = (int)t;
            i = i < 0 ? 0 : (i > (ND - 1) ? (ND - 1) : i);
            acc += f[a * ND + i];
        }
        for (int a = b2s; a <= b2e; ++a) {
            float c = tab[2 * a], s = tab[2 * a + 1];
            float rot = xc * c + yc * s;
            float t = (rot * 0.15915494309189535f) * 729.0f;
            int i = (int)t;
            i = i < 0 ? 0 : (i > (ND - 1) ? (ND - 1) : i);
            acc += f[a * ND + i];
        }
    }
    out[p] = fmaxf(acc * (float)(M_PI / NA), 0.0f);  // clip(.,0,max) == relu
}

extern "C" void kernel_launch(void* const* d_in, const int* in_sizes, int n_in,
                              void* d_out, int out_size, void* d_ws, size_t ws_size,
                              hipStream_t stream) {
    const float* sino = (const float*)d_in[0];
    float* out = (float*)d_out;
    float* ws = (float*)d_ws;

    hipLaunchKernelGGL(k_filter, dim3(NB * NA + 1), dim3(192), 0, stream, sino, ws);
    hipLaunchKernelGGL(k_prefix, dim3(1), dim3(256), 0, stream, ws);
    hipLaunchKernelGGL(k_bp, dim3((NB * HH * WW) / 256), dim3(256), 0, stream, ws, out);
}